// Round 3
// baseline (457.185 us; speedup 1.0000x reference)
//
#include <hip/hip_runtime.h>
#include <hip/hip_bf16.h>

#define FIN 4096
#define FOUT 4096
#define HEADS 4
#define ROWS_PER_HEAD (FOUT / HEADS)  // 1024
#define M_DIM 4096                    // 2*2048 flattened batch*seq

typedef __attribute__((ext_vector_type(8))) short bf16x8;   // 8 bf16 = 4 VGPRs
typedef __attribute__((ext_vector_type(4))) float floatx4;  // MFMA accum

// ---------------------------------------------------------------------------
// Kernel 0: fp32 -> bf16 cast (8 elements/thread, 16B loads x2, 16B store)
// ---------------------------------------------------------------------------
__global__ __launch_bounds__(256) void cast_to_bf16(
    const float* __restrict__ x, __hip_bfloat16* __restrict__ y) {
  int idx = blockIdx.x * 256 + threadIdx.x;  // one per 8 elements
  const float4* xv = (const float4*)x;
  float4 a = xv[idx * 2];
  float4 b = xv[idx * 2 + 1];
  __hip_bfloat16 t[8];
  t[0] = __float2bfloat16(a.x); t[1] = __float2bfloat16(a.y);
  t[2] = __float2bfloat16(a.z); t[3] = __float2bfloat16(a.w);
  t[4] = __float2bfloat16(b.x); t[5] = __float2bfloat16(b.y);
  t[6] = __float2bfloat16(b.z); t[7] = __float2bfloat16(b.w);
  *(bf16x8*)(&y[(size_t)idx * 8]) = *(bf16x8*)t;
}

// ---------------------------------------------------------------------------
// Kernel 1: W_i = conv3x3_per_head(W) + bias + sigmoid(sk)*W    (fp32 -> bf16)
// JAX lax.conv is cross-correlation (no kernel flip); zero padding 1 on both
// dims, head boundaries padded.
// ---------------------------------------------------------------------------
__global__ __launch_bounds__(256) void transform_w(
    const float* __restrict__ W,
    const float* __restrict__ cw,   // [HEADS][3][3]
    const float* __restrict__ cb,   // [HEADS]
    const float* __restrict__ sk,   // [HEADS]
    __hip_bfloat16* __restrict__ Wt) {
  int idx = blockIdx.x * 256 + threadIdx.x;  // 0 .. FOUT*FIN-1
  int f = idx & (FIN - 1);
  int o = idx >> 12;                         // FIN = 4096 = 2^12
  int h = o >> 10;                           // ROWS_PER_HEAD = 1024
  int r = o & (ROWS_PER_HEAD - 1);

  float k[9];
#pragma unroll
  for (int i = 0; i < 9; i++) k[i] = cw[h * 9 + i];
  float sig = 1.0f / (1.0f + __expf(-sk[h]));

  const float* base = W + (size_t)h * ROWS_PER_HEAD * FIN;
  float acc = cb[h];
#pragma unroll
  for (int dr = -1; dr <= 1; dr++) {
    int rr = r + dr;
    if (rr < 0 || rr >= ROWS_PER_HEAD) continue;
#pragma unroll
    for (int df = -1; df <= 1; df++) {
      int ff = f + df;
      if (ff < 0 || ff >= FIN) continue;
      acc += k[(dr + 1) * 3 + (df + 1)] * base[rr * FIN + ff];
    }
  }
  acc += sig * W[idx];
  Wt[idx] = __float2bfloat16(acc);
}

// ---------------------------------------------------------------------------
// Kernel 2: C[m][n] = sum_k A[m][k] * B[n][k]  (NT GEMM, bf16 in, FP32 out)
// m97-structure: 128x128 tile, BK=32, 4 waves, 4x4 mfma_f32_16x16x32_bf16
// per wave, global_load_lds width=16 staging, ds_read_b128 fragments.
// ---------------------------------------------------------------------------
__device__ static inline void gload_lds16(const __hip_bfloat16* g,
                                          __hip_bfloat16* l) {
  __builtin_amdgcn_global_load_lds(
      (const __attribute__((address_space(1))) void*)g,
      (__attribute__((address_space(3))) void*)l, 16, 0, 0);
}

__global__ __launch_bounds__(256) void gemm_nt(
    const __hip_bfloat16* __restrict__ A,  // [M][K]
    const __hip_bfloat16* __restrict__ B,  // [N][K]  (= W_i, row-major)
    float* __restrict__ C,                 // [M][N] fp32
    int M, int N, int K) {
  __shared__ __hip_bfloat16 As[128 * 32];  // 8 KB, unpadded (DMA scatter rule)
  __shared__ __hip_bfloat16 Bs[128 * 32];  // 8 KB

  const int tid = threadIdx.x;
  const int lane = tid & 63;
  const int wave = tid >> 6;  // 0..3
  const int tile_m = blockIdx.y * 128;
  const int tile_n = blockIdx.x * 128;

  const int fr = lane & 15;    // fragment row (m for A, n for B^T)
  const int quad = lane >> 4;  // k-chunk selector (k = quad*8 + j)
  const int wm = (wave & 1) * 64;
  const int wn = (wave >> 1) * 64;

  floatx4 acc[4][4];
#pragma unroll
  for (int i = 0; i < 4; i++)
#pragma unroll
    for (int j = 0; j < 4; j++) acc[i][j] = (floatx4){0.f, 0.f, 0.f, 0.f};

  // Staging: tile is 128 rows x 32 cols bf16 = 512 chunks of 16B.
  // Wave w, iter t covers chunks [(t*4+w)*64, +64); lane l handles chunk
  // base+l; HW writes LDS at (uniform base) + l*16 = chunk (base+l)*16. Match.
  for (int k0 = 0; k0 < K; k0 += 32) {
#pragma unroll
    for (int t = 0; t < 2; t++) {
      int base_chunk = (t * 4 + wave) * 64;     // wave-uniform
      int c = base_chunk + lane;                // per-lane chunk
      int row = c >> 2;
      int kq = (c & 3) * 8;
      gload_lds16(&A[(size_t)(tile_m + row) * K + k0 + kq],
                  &As[base_chunk * 8]);
      gload_lds16(&B[(size_t)(tile_n + row) * K + k0 + kq],
                  &Bs[base_chunk * 8]);
    }
    __syncthreads();

    bf16x8 a_frag[4], b_frag[4];
#pragma unroll
    for (int i = 0; i < 4; i++) {
      a_frag[i] = *(const bf16x8*)(&As[(wm + i * 16 + fr) * 32 + quad * 8]);
      b_frag[i] = *(const bf16x8*)(&Bs[(wn + i * 16 + fr) * 32 + quad * 8]);
    }
#pragma unroll
    for (int i = 0; i < 4; i++)
#pragma unroll
      for (int j = 0; j < 4; j++)
        acc[i][j] = __builtin_amdgcn_mfma_f32_16x16x32_bf16(
            a_frag[i], b_frag[j], acc[i][j], 0, 0, 0);
    __syncthreads();
  }

  // Epilogue: C/D layout col = lane&15, row = quad*4 + reg. FP32 stores.
#pragma unroll
  for (int i = 0; i < 4; i++) {
    int m_base = tile_m + wm + i * 16 + quad * 4;
#pragma unroll
    for (int j = 0; j < 4; j++) {
      int n = tile_n + wn + j * 16 + fr;
#pragma unroll
      for (int r = 0; r < 4; r++) {
        C[(size_t)(m_base + r) * N + n] = acc[i][j][r];
      }
    }
  }
}

// ---------------------------------------------------------------------------
extern "C" void kernel_launch(void* const* d_in, const int* in_sizes, int n_in,
                              void* d_out, int out_size, void* d_ws,
                              size_t ws_size, hipStream_t stream) {
  const float* inp = (const float*)d_in[0];     // [2,2048,4096] fp32
  const float* W = (const float*)d_in[1];       // [4096,4096] fp32
  const float* conv_w = (const float*)d_in[2];  // [4,1,3,3] fp32
  const float* conv_b = (const float*)d_in[3];  // [4] fp32
  const float* sk_wt = (const float*)d_in[4];   // [4,1,1] fp32
  float* out = (float*)d_out;                   // [2,2048,4096] fp32

  __hip_bfloat16* Wt = (__hip_bfloat16*)d_ws;   // 32 MB
  __hip_bfloat16* Ab =
      (__hip_bfloat16*)((char*)d_ws + (size_t)(32u << 20));  // next 32 MB

  // 0) cast activations to bf16
  cast_to_bf16<<<(M_DIM * FIN) / (256 * 8), 256, 0, stream>>>(inp, Ab);
  // 1) transformed weight (bf16) into workspace
  transform_w<<<(FOUT * FIN) / 256, 256, 0, stream>>>(W, conv_w, conv_b, sk_wt,
                                                      Wt);
  // 2) out[m][n] = sum_k Ab[m][k] * Wt[n][k]
  dim3 grid(FOUT / 128, M_DIM / 128);
  gemm_nt<<<grid, 256, 0, stream>>>(Ab, Wt, out, M_DIM, FOUT, FIN);
}

// Round 4
// 326.745 us; speedup vs baseline: 1.3992x; 1.3992x over previous
//
#include <hip/hip_runtime.h>
#include <hip/hip_bf16.h>

#define FIN 4096
#define FOUT 4096
#define HEADS 4
#define ROWS_PER_HEAD (FOUT / HEADS)  // 1024
#define M_DIM 4096                    // 2*2048 flattened batch*seq

typedef __attribute__((ext_vector_type(8))) short bf16x8;   // 8 bf16 = 4 VGPRs
typedef __attribute__((ext_vector_type(4))) float floatx4;  // MFMA accum

// ---------------------------------------------------------------------------
// Kernel 0: fp32 -> bf16 cast (8 elements/thread, 2x16B load, 1x16B store)
// ---------------------------------------------------------------------------
__global__ __launch_bounds__(256) void cast_to_bf16(
    const float* __restrict__ x, __hip_bfloat16* __restrict__ y) {
  int idx = blockIdx.x * 256 + threadIdx.x;  // one per 8 elements
  const float4* xv = (const float4*)x;
  float4 a = xv[idx * 2];
  float4 b = xv[idx * 2 + 1];
  __hip_bfloat16 t[8];
  t[0] = __float2bfloat16(a.x); t[1] = __float2bfloat16(a.y);
  t[2] = __float2bfloat16(a.z); t[3] = __float2bfloat16(a.w);
  t[4] = __float2bfloat16(b.x); t[5] = __float2bfloat16(b.y);
  t[6] = __float2bfloat16(b.z); t[7] = __float2bfloat16(b.w);
  *(bf16x8*)(&y[(size_t)idx * 8]) = *(bf16x8*)t;
}

// ---------------------------------------------------------------------------
// Kernel 1: W_i = conv3x3_per_head(W) + bias + sigmoid(sk)*W    (fp32 -> bf16)
// Vectorized: 8 outputs/thread along fin; float4 row loads + 2 edge scalars;
// bf16x8 (16B) store. Head boundaries zero-padded.
// ---------------------------------------------------------------------------
__global__ __launch_bounds__(256) void transform_w(
    const float* __restrict__ W,
    const float* __restrict__ cw,   // [HEADS][3][3]
    const float* __restrict__ cb,   // [HEADS]
    const float* __restrict__ sk,   // [HEADS]
    __hip_bfloat16* __restrict__ Wt) {
  int gid = blockIdx.x * 256 + threadIdx.x;  // 0 .. FOUT*(FIN/8)-1
  int o = gid >> 9;                          // output row (FIN/8 = 512)
  int fs = (gid & 511) << 3;                 // fin start, multiple of 8
  int h = o >> 10;                           // head
  int r = o & (ROWS_PER_HEAD - 1);

  float kk[3][3];
#pragma unroll
  for (int i = 0; i < 3; i++)
#pragma unroll
    for (int j = 0; j < 3; j++) kk[i][j] = cw[h * 9 + i * 3 + j];
  float sig = 1.0f / (1.0f + __expf(-sk[h]));

  float acc[8];
#pragma unroll
  for (int j = 0; j < 8; j++) acc[j] = cb[h];

#pragma unroll
  for (int dr = -1; dr <= 1; dr++) {
    int rr = r + dr;
    if (rr < 0 || rr >= ROWS_PER_HEAD) continue;
    const float* rp = W + ((size_t)(h * ROWS_PER_HEAD + rr)) * FIN + fs;
    float a[10];
    float4 v0 = *(const float4*)rp;
    float4 v1 = *(const float4*)(rp + 4);
    a[1] = v0.x; a[2] = v0.y; a[3] = v0.z; a[4] = v0.w;
    a[5] = v1.x; a[6] = v1.y; a[7] = v1.z; a[8] = v1.w;
    a[0] = (fs > 0) ? rp[-1] : 0.0f;
    a[9] = (fs + 8 < FIN) ? rp[8] : 0.0f;
#pragma unroll
    for (int j = 0; j < 8; j++)
      acc[j] += kk[dr + 1][0] * a[j] + kk[dr + 1][1] * a[j + 1] +
                kk[dr + 1][2] * a[j + 2];
    if (dr == 0) {
#pragma unroll
      for (int j = 0; j < 8; j++) acc[j] += sig * a[j + 1];
    }
  }
  __hip_bfloat16 t[8];
#pragma unroll
  for (int j = 0; j < 8; j++) t[j] = __float2bfloat16(acc[j]);
  *(bf16x8*)(&Wt[(size_t)o * FIN + fs]) = *(bf16x8*)t;
}

// ---------------------------------------------------------------------------
// Kernel 2: C[m][n] = sum_k A[m][k] * B[n][k]  (NT GEMM, bf16 in, FP32 out)
// m97-structure + XOR chunk swizzle: LDS 16B-chunk position p = row*4 + q'
// stores global k-quad q = q' ^ ((row>>1)&3). Staging DMA dest stays
// wave-uniform-base + lane*16 (required); fragment reads permute koff,
// spreading each 16-lane phase 2-way across all 32 banks (2-way = free).
// ---------------------------------------------------------------------------
__device__ static inline void gload_lds16(const __hip_bfloat16* g,
                                          __hip_bfloat16* l) {
  __builtin_amdgcn_global_load_lds(
      (const __attribute__((address_space(1))) void*)g,
      (__attribute__((address_space(3))) void*)l, 16, 0, 0);
}

__global__ __launch_bounds__(256, 3) void gemm_nt(
    const __hip_bfloat16* __restrict__ A,  // [M][K]
    const __hip_bfloat16* __restrict__ B,  // [N][K]  (= W_i, row-major)
    float* __restrict__ C,                 // [M][N] fp32
    int M, int N, int K) {
  __shared__ __hip_bfloat16 As[128 * 32];  // 8 KB, unpadded (DMA scatter rule)
  __shared__ __hip_bfloat16 Bs[128 * 32];  // 8 KB

  const int tid = threadIdx.x;
  const int lane = tid & 63;
  const int wave = tid >> 6;  // 0..3
  const int tile_m = blockIdx.y * 128;
  const int tile_n = blockIdx.x * 128;

  const int fr = lane & 15;    // fragment row (m for A, n for B^T)
  const int quad = lane >> 4;  // k-chunk selector (k = quad*8 + j)
  const int wm = (wave & 1) * 64;
  const int wn = (wave >> 1) * 64;
  const int sel = (fr >> 1) & 3;          // swizzle selector (row bits 1-2)
  const int koff = (quad ^ sel) * 8;      // swizzled k-offset in LDS row

  floatx4 acc[4][4];
#pragma unroll
  for (int i = 0; i < 4; i++)
#pragma unroll
    for (int j = 0; j < 4; j++) acc[i][j] = (floatx4){0.f, 0.f, 0.f, 0.f};

  for (int k0 = 0; k0 < K; k0 += 32) {
#pragma unroll
    for (int t = 0; t < 2; t++) {
      int base_chunk = (t * 4 + wave) * 64;  // wave-uniform
      int p = base_chunk + lane;             // LDS chunk position
      int row = p >> 2;
      int kq = ((p & 3) ^ ((row >> 1) & 3)) * 8;  // permuted global k-quad
      gload_lds16(&A[(size_t)(tile_m + row) * K + k0 + kq],
                  &As[base_chunk * 8]);
      gload_lds16(&B[(size_t)(tile_n + row) * K + k0 + kq],
                  &Bs[base_chunk * 8]);
    }
    __syncthreads();

    bf16x8 a_frag[4], b_frag[4];
#pragma unroll
    for (int i = 0; i < 4; i++) {
      a_frag[i] = *(const bf16x8*)(&As[(wm + i * 16 + fr) * 32 + koff]);
      b_frag[i] = *(const bf16x8*)(&Bs[(wn + i * 16 + fr) * 32 + koff]);
    }
#pragma unroll
    for (int i = 0; i < 4; i++)
#pragma unroll
      for (int j = 0; j < 4; j++)
        acc[i][j] = __builtin_amdgcn_mfma_f32_16x16x32_bf16(
            a_frag[i], b_frag[j], acc[i][j], 0, 0, 0);
    __syncthreads();
  }

  // Epilogue: C/D layout col = lane&15, row = quad*4 + reg. FP32 stores.
#pragma unroll
  for (int i = 0; i < 4; i++) {
    int m_base = tile_m + wm + i * 16 + quad * 4;
#pragma unroll
    for (int j = 0; j < 4; j++) {
      int n = tile_n + wn + j * 16 + fr;
#pragma unroll
      for (int r = 0; r < 4; r++) {
        C[(size_t)(m_base + r) * N + n] = acc[i][j][r];
      }
    }
  }
}

// ---------------------------------------------------------------------------
extern "C" void kernel_launch(void* const* d_in, const int* in_sizes, int n_in,
                              void* d_out, int out_size, void* d_ws,
                              size_t ws_size, hipStream_t stream) {
  const float* inp = (const float*)d_in[0];     // [2,2048,4096] fp32
  const float* W = (const float*)d_in[1];       // [4096,4096] fp32
  const float* conv_w = (const float*)d_in[2];  // [4,1,3,3] fp32
  const float* conv_b = (const float*)d_in[3];  // [4] fp32
  const float* sk_wt = (const float*)d_in[4];   // [4,1,1] fp32
  float* out = (float*)d_out;                   // [2,2048,4096] fp32

  __hip_bfloat16* Wt = (__hip_bfloat16*)d_ws;   // 32 MB
  __hip_bfloat16* Ab =
      (__hip_bfloat16*)((char*)d_ws + (size_t)(32u << 20));  // next 32 MB

  // 0) cast activations to bf16
  cast_to_bf16<<<(M_DIM * FIN) / (256 * 8), 256, 0, stream>>>(inp, Ab);
  // 1) transformed weight (bf16) into workspace
  transform_w<<<(FOUT * FIN / 8) / 256, 256, 0, stream>>>(W, conv_w, conv_b,
                                                          sk_wt, Wt);
  // 2) out[m][n] = sum_k Ab[m][k] * Wt[n][k]
  dim3 grid(FOUT / 128, M_DIM / 128);
  gemm_nt<<<grid, 256, 0, stream>>>(Ab, Wt, out, M_DIM, FOUT, FIN);
}

// Round 5
// 321.812 us; speedup vs baseline: 1.4207x; 1.0153x over previous
//
#include <hip/hip_runtime.h>
#include <hip/hip_bf16.h>

#define FIN 4096
#define FOUT 4096
#define HEADS 4
#define ROWS_PER_HEAD (FOUT / HEADS)  // 1024
#define M_DIM 4096                    // 2*2048 flattened batch*seq

typedef __attribute__((ext_vector_type(8))) short bf16x8;   // 8 bf16 = 4 VGPRs
typedef __attribute__((ext_vector_type(4))) float floatx4;  // MFMA accum

#define CAST_BLOCKS ((M_DIM * FIN) / (256 * 8))      // 8192
#define TRANS_BLOCKS ((FOUT * FIN / 8) / 256)        // 8192

// ---------------------------------------------------------------------------
// Kernel 1 (merged prep): blocks [0, CAST_BLOCKS) cast inp fp32->bf16;
// blocks [CAST_BLOCKS, +TRANS_BLOCKS) compute W_i = conv3x3 + bias +
// sigmoid(sk)*W (fp32 in, bf16 out). Both paths fully coalesced, 8 elem/thread.
// One launch: both memory-bound jobs share the machine, one less boundary.
// ---------------------------------------------------------------------------
__global__ __launch_bounds__(256) void prep(
    const float* __restrict__ x,    // activations [M_DIM][FIN]
    __hip_bfloat16* __restrict__ y, // bf16 activations out
    const float* __restrict__ W,
    const float* __restrict__ cw,   // [HEADS][3][3]
    const float* __restrict__ cb,   // [HEADS]
    const float* __restrict__ sk,   // [HEADS]
    __hip_bfloat16* __restrict__ Wt) {
  if (blockIdx.x < CAST_BLOCKS) {
    int idx = blockIdx.x * 256 + threadIdx.x;  // one per 8 elements
    const float4* xv = (const float4*)x;
    float4 a = xv[idx * 2];
    float4 b = xv[idx * 2 + 1];
    __hip_bfloat16 t[8];
    t[0] = __float2bfloat16(a.x); t[1] = __float2bfloat16(a.y);
    t[2] = __float2bfloat16(a.z); t[3] = __float2bfloat16(a.w);
    t[4] = __float2bfloat16(b.x); t[5] = __float2bfloat16(b.y);
    t[6] = __float2bfloat16(b.z); t[7] = __float2bfloat16(b.w);
    *(bf16x8*)(&y[(size_t)idx * 8]) = *(bf16x8*)t;
    return;
  }

  int gid = (blockIdx.x - CAST_BLOCKS) * 256 + threadIdx.x;
  int o = gid >> 9;                          // output row (FIN/8 = 512)
  int fs = (gid & 511) << 3;                 // fin start, multiple of 8
  int h = o >> 10;                           // head
  int r = o & (ROWS_PER_HEAD - 1);

  float kk[3][3];
#pragma unroll
  for (int i = 0; i < 3; i++)
#pragma unroll
    for (int j = 0; j < 3; j++) kk[i][j] = cw[h * 9 + i * 3 + j];
  float sig = 1.0f / (1.0f + __expf(-sk[h]));

  float acc[8];
#pragma unroll
  for (int j = 0; j < 8; j++) acc[j] = cb[h];

#pragma unroll
  for (int dr = -1; dr <= 1; dr++) {
    int rr = r + dr;
    if (rr < 0 || rr >= ROWS_PER_HEAD) continue;
    const float* rp = W + ((size_t)(h * ROWS_PER_HEAD + rr)) * FIN + fs;
    float a[10];
    float4 v0 = *(const float4*)rp;
    float4 v1 = *(const float4*)(rp + 4);
    a[1] = v0.x; a[2] = v0.y; a[3] = v0.z; a[4] = v0.w;
    a[5] = v1.x; a[6] = v1.y; a[7] = v1.z; a[8] = v1.w;
    a[0] = (fs > 0) ? rp[-1] : 0.0f;
    a[9] = (fs + 8 < FIN) ? rp[8] : 0.0f;
#pragma unroll
    for (int j = 0; j < 8; j++)
      acc[j] += kk[dr + 1][0] * a[j] + kk[dr + 1][1] * a[j + 1] +
                kk[dr + 1][2] * a[j + 2];
    if (dr == 0) {
#pragma unroll
      for (int j = 0; j < 8; j++) acc[j] += sig * a[j + 1];
    }
  }
  __hip_bfloat16 t[8];
#pragma unroll
  for (int j = 0; j < 8; j++) t[j] = __float2bfloat16(acc[j]);
  *(bf16x8*)(&Wt[(size_t)o * FIN + fs]) = *(bf16x8*)t;
}

// ---------------------------------------------------------------------------
// Kernel 2: C[m][n] = sum_k A[m][k] * B[n][k]  (NT GEMM, bf16 in, FP32 out)
// m97-structure + XOR chunk swizzle (verified R4: SQ_LDS_BANK_CONFLICT = 0).
// LDS 16B-chunk position p = row*4 + q' stores global k-quad
// q = q' ^ ((row>>1)&3); fragment reads permute koff to match.
// ---------------------------------------------------------------------------
__device__ static inline void gload_lds16(const __hip_bfloat16* g,
                                          __hip_bfloat16* l) {
  __builtin_amdgcn_global_load_lds(
      (const __attribute__((address_space(1))) void*)g,
      (__attribute__((address_space(3))) void*)l, 16, 0, 0);
}

__global__ __launch_bounds__(256, 3) void gemm_nt(
    const __hip_bfloat16* __restrict__ A,  // [M][K]
    const __hip_bfloat16* __restrict__ B,  // [N][K]  (= W_i, row-major)
    float* __restrict__ C,                 // [M][N] fp32
    int M, int N, int K) {
  __shared__ __hip_bfloat16 As[128 * 32];  // 8 KB, unpadded (DMA scatter rule)
  __shared__ __hip_bfloat16 Bs[128 * 32];  // 8 KB

  const int tid = threadIdx.x;
  const int lane = tid & 63;
  const int wave = tid >> 6;  // 0..3
  const int tile_m = blockIdx.y * 128;
  const int tile_n = blockIdx.x * 128;

  const int fr = lane & 15;    // fragment row (m for A, n for B^T)
  const int quad = lane >> 4;  // k-chunk selector (k = quad*8 + j)
  const int wm = (wave & 1) * 64;
  const int wn = (wave >> 1) * 64;
  const int sel = (fr >> 1) & 3;          // swizzle selector (row bits 1-2)
  const int koff = (quad ^ sel) * 8;      // swizzled k-offset in LDS row

  floatx4 acc[4][4];
#pragma unroll
  for (int i = 0; i < 4; i++)
#pragma unroll
    for (int j = 0; j < 4; j++) acc[i][j] = (floatx4){0.f, 0.f, 0.f, 0.f};

  for (int k0 = 0; k0 < K; k0 += 32) {
#pragma unroll
    for (int t = 0; t < 2; t++) {
      int base_chunk = (t * 4 + wave) * 64;  // wave-uniform
      int p = base_chunk + lane;             // LDS chunk position
      int row = p >> 2;
      int kq = ((p & 3) ^ ((row >> 1) & 3)) * 8;  // permuted global k-quad
      gload_lds16(&A[(size_t)(tile_m + row) * K + k0 + kq],
                  &As[base_chunk * 8]);
      gload_lds16(&B[(size_t)(tile_n + row) * K + k0 + kq],
                  &Bs[base_chunk * 8]);
    }
    __syncthreads();

    bf16x8 a_frag[4], b_frag[4];
#pragma unroll
    for (int i = 0; i < 4; i++) {
      a_frag[i] = *(const bf16x8*)(&As[(wm + i * 16 + fr) * 32 + koff]);
      b_frag[i] = *(const bf16x8*)(&Bs[(wn + i * 16 + fr) * 32 + koff]);
    }
#pragma unroll
    for (int i = 0; i < 4; i++)
#pragma unroll
      for (int j = 0; j < 4; j++)
        acc[i][j] = __builtin_amdgcn_mfma_f32_16x16x32_bf16(
            a_frag[i], b_frag[j], acc[i][j], 0, 0, 0);
    __syncthreads();
  }

  // Epilogue: C/D layout col = lane&15, row = quad*4 + reg. FP32 stores.
#pragma unroll
  for (int i = 0; i < 4; i++) {
    int m_base = tile_m + wm + i * 16 + quad * 4;
#pragma unroll
    for (int j = 0; j < 4; j++) {
      int n = tile_n + wn + j * 16 + fr;
#pragma unroll
      for (int r = 0; r < 4; r++) {
        C[(size_t)(m_base + r) * N + n] = acc[i][j][r];
      }
    }
  }
}

// ---------------------------------------------------------------------------
extern "C" void kernel_launch(void* const* d_in, const int* in_sizes, int n_in,
                              void* d_out, int out_size, void* d_ws,
                              size_t ws_size, hipStream_t stream) {
  const float* inp = (const float*)d_in[0];     // [2,2048,4096] fp32
  const float* W = (const float*)d_in[1];       // [4096,4096] fp32
  const float* conv_w = (const float*)d_in[2];  // [4,1,3,3] fp32
  const float* conv_b = (const float*)d_in[3];  // [4] fp32
  const float* sk_wt = (const float*)d_in[4];   // [4,1,1] fp32
  float* out = (float*)d_out;                   // [2,2048,4096] fp32

  __hip_bfloat16* Wt = (__hip_bfloat16*)d_ws;   // 32 MB
  __hip_bfloat16* Ab =
      (__hip_bfloat16*)((char*)d_ws + (size_t)(32u << 20));  // next 32 MB

  // 1) merged prep: cast activations + transform weight, one launch
  prep<<<CAST_BLOCKS + TRANS_BLOCKS, 256, 0, stream>>>(inp, Ab, W, conv_w,
                                                       conv_b, sk_wt, Wt);
  // 2) out[m][n] = sum_k Ab[m][k] * Wt[n][k]
  dim3 grid(FOUT / 128, M_DIM / 128);
  gemm_nt<<<grid, 256, 0, stream>>>(Ab, Wt, out, M_DIM, FOUT, FIN);
}